// Round 1
// baseline (3458.907 us; speedup 1.0000x reference)
//
#include <hip/hip_runtime.h>
#include <math.h>

#define NB 8
#define NS 1024
#define NE 1024
#define NH 16
#define ND 64
#define NL 1024

// ---------------- GEMM: C = A @ W^T ----------------
// A: [M,K] row-major, W: [N,K] row-major.
// MODE 0: scatter-store C[m,n] -> out[((b*H+h)*S+s)*D+d] with m=b*S+s, n=h*D+d
// MODE 1: row-major C[m*N+n]
template<int MODE>
__global__ __launch_bounds__(256)
void gemm_abt(const float* __restrict__ A, const float* __restrict__ W,
              float* __restrict__ C, int M, int N, int K)
{
    // transposed LDS tiles: [k][m] / [k][n] so inner loop reads are float4
    __shared__ __align__(16) float As[16][68];
    __shared__ __align__(16) float Bs[16][68];
    const int tid  = threadIdx.x;
    const int m0   = blockIdx.x * 64;
    const int n0   = blockIdx.y * 64;
    const int tx   = tid & 15;        // n-dir (4 cols each)
    const int ty   = tid >> 4;        // m-dir (4 rows each)
    const int lrow = tid >> 2;        // 0..63 (load row)
    const int lk   = (tid & 3) * 4;   // 0,4,8,12 (load k quad)

    float acc[4][4] = {};

    for (int k0 = 0; k0 < K; k0 += 16) {
        float4 av = *(const float4*)&A[(size_t)(m0 + lrow) * K + k0 + lk];
        float4 bv = *(const float4*)&W[(size_t)(n0 + lrow) * K + k0 + lk];
        __syncthreads();
        As[lk + 0][lrow] = av.x; As[lk + 1][lrow] = av.y;
        As[lk + 2][lrow] = av.z; As[lk + 3][lrow] = av.w;
        Bs[lk + 0][lrow] = bv.x; Bs[lk + 1][lrow] = bv.y;
        Bs[lk + 2][lrow] = bv.z; Bs[lk + 3][lrow] = bv.w;
        __syncthreads();
        #pragma unroll
        for (int kk = 0; kk < 16; ++kk) {
            float4 a4 = *(const float4*)&As[kk][ty * 4];
            float4 b4 = *(const float4*)&Bs[kk][tx * 4];
            float a_[4] = {a4.x, a4.y, a4.z, a4.w};
            float b_[4] = {b4.x, b4.y, b4.z, b4.w};
            #pragma unroll
            for (int i = 0; i < 4; ++i)
                #pragma unroll
                for (int j = 0; j < 4; ++j)
                    acc[i][j] = fmaf(a_[i], b_[j], acc[i][j]);
        }
    }

    #pragma unroll
    for (int i = 0; i < 4; ++i) {
        const int m = m0 + ty * 4 + i;
        #pragma unroll
        for (int j = 0; j < 4; ++j) {
            const int n = n0 + tx * 4 + j;
            if (MODE == 0) {
                const int b = m >> 10, s = m & 1023;
                const int h = n >> 6,  d = n & 63;
                C[(((size_t)b * NH + h) * NS + s) * ND + d] = acc[i][j];
            } else {
                C[(size_t)m * N + n] = acc[i][j];
            }
        }
    }
}

// ---------------- fused causal attention with RPE ----------------
// Block: 256 threads handles one (b,h) and 32 query rows.
// thread: r = tid>>3 (row in tile), c = tid&7 (owns d-slice c*8..c*8+7)
__global__ __launch_bounds__(256)
void attn_kernel(const float* __restrict__ Q, const float* __restrict__ K,
                 const float* __restrict__ V, const float* __restrict__ PEK,
                 const float* __restrict__ PEV, float* __restrict__ O)
{
    const int st = blockIdx.x;            // 0..31 (s-tile)
    const int bh = blockIdx.y;            // 0..127
    const int b  = bh >> 4, h = bh & 15;
    // permuted q index for the RPE-score term (replicates torch view semantics)
    const int n2 = h * NB + b;
    const int b2 = n2 >> 4, h2 = n2 & 15;
    const int s0 = st * 32;

    const int tid   = threadIdx.x;
    const int r     = tid >> 3;           // 0..31
    const int c     = tid & 7;            // 0..7
    const int dbase = c * 8;

    __shared__ __align__(16) float k_s[32][68];
    __shared__ __align__(16) float v_s[32][68];
    __shared__ __align__(16) float pek_s[64][68];
    __shared__ __align__(16) float pev_s[64][68];

    const float* qrow  = Q + ((size_t)bh * NS + s0 + r) * ND;
    const float* qprow = Q + (((size_t)b2 * NH + h2) * NS + s0 + r) * ND;
    const float4 q4a = *(const float4*)&qrow[dbase];
    const float4 q4b = *(const float4*)&qrow[dbase + 4];
    const float4 p4a = *(const float4*)&qprow[dbase];
    const float4 p4b = *(const float4*)&qprow[dbase + 4];

    const float* kbase = K + (size_t)bh * NS * ND;
    const float* vbase = V + (size_t)bh * NS * ND;

    float m = -1e30f, l = 0.f;
    float4 acc0 = {0.f,0.f,0.f,0.f}, acc1 = {0.f,0.f,0.f,0.f};
    float sreg[32];

    for (int t0 = 0; t0 <= s0; t0 += 32) {
        const int relbase = t0 - s0 + NL - 31;   // >= 1, +63 <= 1056 (< 2049)
        __syncthreads();   // previous iteration done reading tiles
        #pragma unroll
        for (int i = 0; i < 2; ++i) {
            const int pos = tid + 256 * i;
            const int row = pos >> 4, c4 = (pos & 15) * 4;
            *(float4*)&k_s[row][c4] = *(const float4*)&kbase[(size_t)(t0 + row) * ND + c4];
            *(float4*)&v_s[row][c4] = *(const float4*)&vbase[(size_t)(t0 + row) * ND + c4];
        }
        #pragma unroll
        for (int i = 0; i < 4; ++i) {
            const int pos = tid + 256 * i;
            const int row = pos >> 4, c4 = (pos & 15) * 4;
            *(float4*)&pek_s[row][c4] = *(const float4*)&PEK[(size_t)(relbase + row) * ND + c4];
            *(float4*)&pev_s[row][c4] = *(const float4*)&PEV[(size_t)(relbase + row) * ND + c4];
        }
        __syncthreads();

        // pass 1: scores for 32 t's (partial dot over this lane's d-slice,
        // then 8-lane shfl reduce -> every lane of the row has full score)
        float tmax = -1e30f;
        #pragma unroll
        for (int tt = 0; tt < 32; ++tt) {
            const int u = tt - r + 31;   // 0..62
            const float4 k4a = *(const float4*)&k_s[tt][dbase];
            const float4 k4b = *(const float4*)&k_s[tt][dbase + 4];
            const float4 e4a = *(const float4*)&pek_s[u][dbase];
            const float4 e4b = *(const float4*)&pek_s[u][dbase + 4];
            float part = q4a.x*k4a.x + q4a.y*k4a.y + q4a.z*k4a.z + q4a.w*k4a.w
                       + q4b.x*k4b.x + q4b.y*k4b.y + q4b.z*k4b.z + q4b.w*k4b.w
                       + p4a.x*e4a.x + p4a.y*e4a.y + p4a.z*e4a.z + p4a.w*e4a.w
                       + p4b.x*e4b.x + p4b.y*e4b.y + p4b.z*e4b.z + p4b.w*e4b.w;
            part += __shfl_xor(part, 1);
            part += __shfl_xor(part, 2);
            part += __shfl_xor(part, 4);
            part *= 0.125f;                        // 1/SCALE
            if (t0 + tt > s0 + r) part = -1e30f;   // causal mask
            sreg[tt] = part;
            tmax = fmaxf(tmax, part);
        }

        const float mnew  = fmaxf(m, tmax);
        const float scale = __expf(m - mnew);
        m = mnew;
        l *= scale;
        acc0.x *= scale; acc0.y *= scale; acc0.z *= scale; acc0.w *= scale;
        acc1.x *= scale; acc1.y *= scale; acc1.z *= scale; acc1.w *= scale;

        // pass 2: p = exp(s-m); accumulate p * (v + pev)
        #pragma unroll
        for (int tt = 0; tt < 32; ++tt) {
            const float p = __expf(sreg[tt] - mnew);
            l += p;
            const int u = tt - r + 31;
            const float4 v4a = *(const float4*)&v_s[tt][dbase];
            const float4 v4b = *(const float4*)&v_s[tt][dbase + 4];
            const float4 f4a = *(const float4*)&pev_s[u][dbase];
            const float4 f4b = *(const float4*)&pev_s[u][dbase + 4];
            acc0.x += p * (v4a.x + f4a.x); acc0.y += p * (v4a.y + f4a.y);
            acc0.z += p * (v4a.z + f4a.z); acc0.w += p * (v4a.w + f4a.w);
            acc1.x += p * (v4b.x + f4b.x); acc1.y += p * (v4b.y + f4b.y);
            acc1.z += p * (v4b.z + f4b.z); acc1.w += p * (v4b.w + f4b.w);
        }
    }

    const float inv = 1.0f / l;
    float* orow = O + ((size_t)(b * NS + s0 + r)) * NE + h * ND + dbase;
    float4 o0, o1;
    o0.x = acc0.x * inv; o0.y = acc0.y * inv; o0.z = acc0.z * inv; o0.w = acc0.w * inv;
    o1.x = acc1.x * inv; o1.y = acc1.y * inv; o1.z = acc1.z * inv; o1.w = acc1.w * inv;
    *(float4*)&orow[0] = o0;
    *(float4*)&orow[4] = o1;
}

extern "C" void kernel_launch(void* const* d_in, const int* in_sizes, int n_in,
                              void* d_out, int out_size, void* d_ws, size_t ws_size,
                              hipStream_t stream) {
    const float* x   = (const float*)d_in[0];
    // d_in[1] is the causal mask (bool) -- implied by t<=s, unused
    const float* Wq  = (const float*)d_in[2];
    const float* Wk  = (const float*)d_in[3];
    const float* Wv  = (const float*)d_in[4];
    const float* Wo  = (const float*)d_in[5];
    const float* pek = (const float*)d_in[6];
    const float* pev = (const float*)d_in[7];

    float* ws = (float*)d_ws;
    float* q  = ws;                          // [B,H,S,D] 8.4M floats
    float* k  = ws + (size_t)8388608;
    float* v  = ws + (size_t)16777216;
    float* ao = ws + (size_t)25165824;       // [B,S,E]
    float* out = (float*)d_out;

    dim3 blk(256);
    dim3 g1(128, 16);
    gemm_abt<0><<<g1, blk, 0, stream>>>(x, Wq, q, NB * NS, NE, NE);
    gemm_abt<0><<<g1, blk, 0, stream>>>(x, Wk, k, NB * NS, NE, NE);
    gemm_abt<0><<<g1, blk, 0, stream>>>(x, Wv, v, NB * NS, NE, NE);

    dim3 g2(NS / 32, NB * NH);
    attn_kernel<<<g2, blk, 0, stream>>>(q, k, v, pek, pev, ao);

    gemm_abt<1><<<g1, blk, 0, stream>>>(ao, Wo, out, NB * NS, NE, NE);
}

// Round 2
// 1093.844 us; speedup vs baseline: 3.1622x; 3.1622x over previous
//
#include <hip/hip_runtime.h>
#include <math.h>

#define NB 8
#define NS 1024
#define NE 1024
#define NH 16
#define ND 64
#define NL 1024

typedef __attribute__((ext_vector_type(8))) short short8;
typedef __attribute__((ext_vector_type(16))) float f32x16;

__device__ __forceinline__ ushort f2bf(float f) {
    union { float f; unsigned u; } v; v.f = f;
    unsigned r = v.u + 0x7fffu + ((v.u >> 16) & 1u);
    return (ushort)(r >> 16);
}

// ---------------- GEMM: C = A @ W^T ----------------
// A: [M,K]=[8192,1024] fp32, W: [N,K]=[1024,1024] fp32.
// MODE 0: bf16 scatter-store -> [B,H,S,D]
// MODE 1: fp32 row-major [M,N]
// MODE 2: bf16 scatter-store transposed -> [B,H,D,S]
template<int MODE>
__global__ __launch_bounds__(256)
void gemm_abt(const float* __restrict__ A, const float* __restrict__ W,
              float* __restrict__ Cf, ushort* __restrict__ Cb, int K)
{
    __shared__ __align__(16) float As[16][68];
    __shared__ __align__(16) float Bs[16][68];
    const int tid  = threadIdx.x;
    const int m0   = blockIdx.x * 64;
    const int n0   = blockIdx.y * 64;
    const int tx   = tid & 15;
    const int ty   = tid >> 4;
    const int lrow = tid >> 2;
    const int lk   = (tid & 3) * 4;

    float acc[4][4] = {};

    for (int k0 = 0; k0 < K; k0 += 16) {
        float4 av = *(const float4*)&A[(size_t)(m0 + lrow) * K + k0 + lk];
        float4 bv = *(const float4*)&W[(size_t)(n0 + lrow) * K + k0 + lk];
        __syncthreads();
        As[lk + 0][lrow] = av.x; As[lk + 1][lrow] = av.y;
        As[lk + 2][lrow] = av.z; As[lk + 3][lrow] = av.w;
        Bs[lk + 0][lrow] = bv.x; Bs[lk + 1][lrow] = bv.y;
        Bs[lk + 2][lrow] = bv.z; Bs[lk + 3][lrow] = bv.w;
        __syncthreads();
        #pragma unroll
        for (int kk = 0; kk < 16; ++kk) {
            float4 a4 = *(const float4*)&As[kk][ty * 4];
            float4 b4 = *(const float4*)&Bs[kk][tx * 4];
            float a_[4] = {a4.x, a4.y, a4.z, a4.w};
            float b_[4] = {b4.x, b4.y, b4.z, b4.w};
            #pragma unroll
            for (int i = 0; i < 4; ++i)
                #pragma unroll
                for (int j = 0; j < 4; ++j)
                    acc[i][j] = fmaf(a_[i], b_[j], acc[i][j]);
        }
    }

    #pragma unroll
    for (int i = 0; i < 4; ++i) {
        const int m = m0 + ty * 4 + i;
        #pragma unroll
        for (int j = 0; j < 4; ++j) {
            const int n = n0 + tx * 4 + j;
            if (MODE == 0) {
                const int b = m >> 10, s = m & 1023;
                const int h = n >> 6,  d = n & 63;
                Cb[(((size_t)b * NH + h) * NS + s) * ND + d] = f2bf(acc[i][j]);
            } else if (MODE == 2) {
                const int b = m >> 10, s = m & 1023;
                const int h = n >> 6,  d = n & 63;
                Cb[(((size_t)b * NH + h) * ND + d) * NS + s] = f2bf(acc[i][j]);
            } else {
                Cf[(size_t)m * NE + n] = acc[i][j];
            }
        }
    }
}

// ---------------- cast kernels ----------------
__global__ __launch_bounds__(256)
void cast_pek(const float* __restrict__ pek, ushort* __restrict__ out, int n) {
    int i = blockIdx.x * 256 + threadIdx.x;
    if (i < n) out[i] = f2bf(pek[i]);
}

// PEVTs[d][r'] = bf16(PEV[r'+1][d]), r' in [0,1056)
__global__ __launch_bounds__(256)
void cast_pevt(const float* __restrict__ pev, ushort* __restrict__ out) {
    int i = blockIdx.x * 256 + threadIdx.x;
    if (i >= 64 * 1056) return;
    int d = i / 1056, r = i % 1056;
    out[(size_t)d * 1056 + r] = f2bf(pev[(size_t)(r + 1) * ND + d]);
}

// ---------------- MFMA fused attention with RPE ----------------
// 1 wave / block; block handles (b,h) and 32 query rows (s-tile).
// lane: sl = lane&31 owns q-row s0+sl; hi = lane>>5.
// Swapped QK: Csw[t,s] = mfma(Kfrag, Qfrag) -> softmax lane-local.
// Score RPE via M[s,u]=Q2·PEK_win^T gather; value RPE via skew-GEMM on Pskew.
__global__ __launch_bounds__(64)
void attn_mfma(const ushort* __restrict__ Qb, const ushort* __restrict__ Kb,
               const ushort* __restrict__ VTb, const ushort* __restrict__ PEKb,
               const ushort* __restrict__ PEVTs, float* __restrict__ AO)
{
    const int idx = blockIdx.x;
    const int st  = 31 - (idx >> 7);     // longest blocks first
    const int bh  = idx & 127;
    const int b   = bh >> 4, h = bh & 15;
    const int n2  = h * NB + b;          // torch view(S,H,B,S).transpose(0,2) shuffle
    const int b2  = n2 >> 4, h2 = n2 & 15;
    const int s0  = st * 32;

    const int lane = threadIdx.x;
    const int sl   = lane & 31;
    const int hi   = lane >> 5;

    __shared__ __align__(16) float  Mb[32][66];   // 8448 B  (read stride 65 ≡ 1 mod 32)
    __shared__ __align__(16) ushort Pb[32][72];   // 4608 B  (rows 144 B, 16B-aligned)

    // zero Pb once; written positions are iteration-invariant
    for (int t = lane; t < 32 * 72 / 2; t += 64) ((int*)Pb)[t] = 0;

    // Q / Q2 fragments (B-operand layout: lane holds Q[s0+sl][16c+8hi+j])
    const ushort* qptr  = Qb + (((size_t)bh * NS) + s0 + sl) * ND + hi * 8;
    const ushort* q2ptr = Qb + ((((size_t)b2 * NH + h2) * NS) + s0 + sl) * ND + hi * 8;
    short8 qf[4], q2f[4];
    #pragma unroll
    for (int c = 0; c < 4; ++c) {
        qf[c]  = *(const short8*)(qptr  + 16 * c);
        q2f[c] = *(const short8*)(q2ptr + 16 * c);
    }

    const ushort* kbase  = Kb  + (size_t)bh * NS * ND;
    const ushort* vtbase = VTb + (size_t)bh * ND * NS;

    f32x16 acc0 = {}, acc1 = {};
    float mrow = -1e30f, lrow = 0.f;

    for (int i = 0; i <= st; ++i) {
        const int t0 = i * 32;
        const int R0 = t0 - s0 + NL - 31;   // pek row base; R0-1 ≡ 0 mod 32

        // ---- QK^T (swapped): Csw[t,s] ----
        f32x16 csw = {};
        const ushort* kptr = kbase + (size_t)(t0 + sl) * ND + hi * 8;
        #pragma unroll
        for (int c = 0; c < 4; ++c) {
            short8 kf = *(const short8*)(kptr + 16 * c);
            csw = __builtin_amdgcn_mfma_f32_32x32x16_bf16(kf, qf[c], csw, 0, 0, 0);
        }

        // ---- M chunks: M[s, u] = q2[s]·pek[R0+u], u in [0,64) ----
        #pragma unroll
        for (int ch = 0; ch < 2; ++ch) {
            f32x16 cm = {};
            const ushort* pptr = PEKb + (size_t)(R0 + ch * 32 + sl) * ND + hi * 8;
            #pragma unroll
            for (int c = 0; c < 4; ++c) {
                short8 ef = *(const short8*)(pptr + 16 * c);
                cm = __builtin_amdgcn_mfma_f32_32x32x16_bf16(q2f[c], ef, cm, 0, 0, 0);
            }
            #pragma unroll
            for (int q = 0; q < 16; ++q) {
                const int srow = (q & 3) + 8 * (q >> 2) + 4 * hi;
                Mb[srow][ch * 32 + sl] = cm[q];
            }
        }
        __syncthreads();

        // ---- gather RPE + mask + online softmax (lane owns row s0+sl) ----
        float sc[16], tmax = -1e30f;
        #pragma unroll
        for (int q = 0; q < 16; ++q) {
            const int trow = (q & 3) + 8 * (q >> 2) + 4 * hi;
            const int u = trow + 31 - sl;           // t_l - s_l + 31
            float v = (csw[q] + Mb[sl][u]) * 0.125f;
            if (t0 + trow > s0 + sl) v = -1e30f;
            sc[q] = v;
            tmax = fmaxf(tmax, v);
        }
        tmax = fmaxf(tmax, __shfl_xor(tmax, 32));
        const float mnew = fmaxf(mrow, tmax);
        const float r = __expf(mrow - mnew);
        float ps[16], lsum = 0.f;
        #pragma unroll
        for (int q = 0; q < 16; ++q) { ps[q] = __expf(sc[q] - mnew); lsum += ps[q]; }
        lsum += __shfl_xor(lsum, 32);
        lrow = lrow * r + lsum;
        mrow = mnew;
        acc0 *= r; acc1 *= r;

        // ---- write Pskew (bf16): Pb[sl][trow+31-sl] = p ----
        #pragma unroll
        for (int q = 0; q < 16; ++q) {
            const int trow = (q & 3) + 8 * (q >> 2) + 4 * hi;
            Pb[sl][trow + 31 - sl] = f2bf(ps[q]);
        }
        __syncthreads();

        // ---- PV: O^T += V^T · P^T  (P^T B-frag assembled via shfl) ----
        float sh[16];
        #pragma unroll
        for (int q = 0; q < 16; ++q) sh[q] = __shfl_xor(ps[q], 32);
        #pragma unroll
        for (int c = 0; c < 2; ++c) {
            short8 bfrag;
            #pragma unroll
            for (int j = 0; j < 8; ++j) {
                float pv;
                if (j < 4) pv = hi ? sh[8 * c + 4 + j] : ps[8 * c + j];
                else       pv = hi ? ps[8 * c + j]     : sh[8 * c + j - 4];
                bfrag[j] = (short)f2bf(pv);
            }
            const ushort* vt0 = vtbase + (size_t)sl * NS + t0 + 16 * c + 8 * hi;
            short8 va0 = *(const short8*)(vt0);
            short8 va1 = *(const short8*)(vt0 + 32 * NS);
            acc0 = __builtin_amdgcn_mfma_f32_32x32x16_bf16(va0, bfrag, acc0, 0, 0, 0);
            acc1 = __builtin_amdgcn_mfma_f32_32x32x16_bf16(va1, bfrag, acc1, 0, 0, 0);
        }

        // ---- value-RPE skew GEMM: O^T += PEVT · Pskew^T ----
        #pragma unroll
        for (int c = 0; c < 4; ++c) {
            short8 pskew = *(const short8*)&Pb[sl][16 * c + 8 * hi];
            const ushort* pv0 = PEVTs + (size_t)sl * 1056 + (R0 - 1) + 16 * c + 8 * hi;
            short8 ea0 = *(const short8*)(pv0);
            short8 ea1 = *(const short8*)(pv0 + (size_t)32 * 1056);
            acc0 = __builtin_amdgcn_mfma_f32_32x32x16_bf16(ea0, pskew, acc0, 0, 0, 0);
            acc1 = __builtin_amdgcn_mfma_f32_32x32x16_bf16(ea1, pskew, acc1, 0, 0, 0);
        }
    }

    // ---- epilogue: O[s0+sl][d] = acc^T / l ----
    const float inv = 1.0f / lrow;
    float* orow = AO + ((size_t)b * NS + s0 + sl) * NE + h * ND;
    #pragma unroll
    for (int q = 0; q < 16; ++q) {
        const int dr = (q & 3) + 8 * (q >> 2) + 4 * hi;
        orow[dr]      = acc0[q] * inv;
        orow[dr + 32] = acc1[q] * inv;
    }
}

extern "C" void kernel_launch(void* const* d_in, const int* in_sizes, int n_in,
                              void* d_out, int out_size, void* d_ws, size_t ws_size,
                              hipStream_t stream) {
    const float* x   = (const float*)d_in[0];
    const float* Wq  = (const float*)d_in[2];
    const float* Wk  = (const float*)d_in[3];
    const float* Wv  = (const float*)d_in[4];
    const float* Wo  = (const float*)d_in[5];
    const float* pek = (const float*)d_in[6];
    const float* pev = (const float*)d_in[7];

    ushort* ws16 = (ushort*)d_ws;
    ushort* Qb    = ws16;                         // [B,H,S,D] bf16  (8.39M)
    ushort* Kbf   = ws16 + (size_t)8388608;
    ushort* VTb   = ws16 + (size_t)16777216;      // [B,H,D,S] bf16
    ushort* PEKb  = ws16 + (size_t)25165824;      // [2049,64] bf16
    ushort* PEVTs = ws16 + (size_t)25296960;      // [64,1056] bf16 (shifted by 1)
    float*  ao    = (float*)(ws16 + (size_t)25364544);   // [B,S,E] fp32
    float*  out   = (float*)d_out;

    dim3 blk(256);
    dim3 g1(128, 16);
    gemm_abt<0><<<g1, blk, 0, stream>>>(x, Wq, nullptr, Qb,  NE);
    gemm_abt<0><<<g1, blk, 0, stream>>>(x, Wk, nullptr, Kbf, NE);
    gemm_abt<2><<<g1, blk, 0, stream>>>(x, Wv, nullptr, VTb, NE);

    cast_pek<<<(2049 * 64 + 255) / 256, blk, 0, stream>>>(pek, PEKb, 2049 * 64);
    cast_pevt<<<(64 * 1056 + 255) / 256, blk, 0, stream>>>(pev, PEVTs);

    attn_mfma<<<dim3(4096), dim3(64), 0, stream>>>(Qb, Kbf, VTb, PEKb, PEVTs, ao);

    gemm_abt<1><<<g1, blk, 0, stream>>>(ao, Wo, out, nullptr, NE);
}

// Round 3
// 291.636 us; speedup vs baseline: 11.8604x; 3.7507x over previous
//
#include <hip/hip_runtime.h>
#include <math.h>

#define NB 8
#define NS 1024
#define NE 1024
#define NH 16
#define ND 64
#define NL 1024

typedef __attribute__((ext_vector_type(8))) short short8;
typedef __attribute__((ext_vector_type(4))) float f32x4;
typedef __attribute__((ext_vector_type(16))) float f32x16;

__device__ __forceinline__ ushort f2bf(float f) {
    union { float f; unsigned u; } v; v.f = f;
    unsigned r = v.u + 0x7fffu + ((v.u >> 16) & 1u);
    return (ushort)(r >> 16);
}

__device__ __forceinline__ void stage16(const ushort* gsrc, ushort* lbase) {
    __builtin_amdgcn_global_load_lds((const __attribute__((address_space(1))) void*)gsrc,
                                     (__attribute__((address_space(3))) void*)lbase,
                                     16, 0, 0);
}

// ---------------- casts ----------------
__global__ __launch_bounds__(256)
void cast_f2b4(const float* __restrict__ in, ushort* __restrict__ out, int n4) {
    int i = blockIdx.x * 256 + threadIdx.x;
    if (i >= n4) return;
    float4 v = ((const float4*)in)[i];
    ushort4 o = make_ushort4(f2bf(v.x), f2bf(v.y), f2bf(v.z), f2bf(v.w));
    ((ushort4*)out)[i] = o;
}

__global__ __launch_bounds__(256)
void cast_pek(const float* __restrict__ pek, ushort* __restrict__ out, int n) {
    int i = blockIdx.x * 256 + threadIdx.x;
    if (i < n) out[i] = f2bf(pek[i]);
}

// PEVTs[d][r'] = bf16(PEV[r'+1][d]), r' in [0,1056)
__global__ __launch_bounds__(256)
void cast_pevt(const float* __restrict__ pev, ushort* __restrict__ out) {
    int i = blockIdx.x * 256 + threadIdx.x;
    if (i >= 64 * 1056) return;
    int d = i / 1056, r = i % 1056;
    out[(size_t)d * 1056 + r] = f2bf(pev[(size_t)(r + 1) * ND + d]);
}

// ---------------- MFMA GEMM: C = A @ W^T (bf16 in, fp32 acc) ----------------
// A: [M,1024] bf16, W: [N,1024] bf16. 128x128 tile, BK=32, 4 waves (2x2 of 64x64).
// MODE 0: bf16 scatter -> [B,H,S,D] (m=b*S+s, n=h*D+d)
// MODE 1: fp32 row-major [M,1024]
// MODE 3: operands are (Wv, x): m=(h,d), n=(b,s); bf16 -> [B,H,D,S] (lane-contiguous s)
template<int MODE>
__global__ __launch_bounds__(256)
void gemm_mfma(const ushort* __restrict__ A, const ushort* __restrict__ W,
               float* __restrict__ Cf, ushort* __restrict__ Cb)
{
    constexpr int K = 1024;
    __shared__ __align__(16) ushort As[128 * 32];
    __shared__ __align__(16) ushort Bs[128 * 32];
    const int tid = threadIdx.x;
    const int w   = tid >> 6;
    const int l   = tid & 63;
    const int m0  = blockIdx.x * 128;
    const int n0  = blockIdx.y * 128;
    const int wr  = w >> 1, wc = w & 1;

    // staging: call c covers rows [64c+16w .. 64c+16w+16), lane l -> row +(l>>2), col (l&3)*8
    const int srow = 16 * w + (l >> 2);
    const int scol = (l & 3) * 8;
    const ushort* aptr = A + (size_t)(m0 + srow) * K + scol;
    const ushort* bptr = W + (size_t)(n0 + srow) * K + scol;
    ushort* asl = &As[w * 512];   // wave-uniform LDS base (+2048 for c=1)
    ushort* bsl = &Bs[w * 512];

    const int fl = l & 15, fk = (l >> 4) * 8;

    f32x4 acc[4][4] = {};

    for (int k0 = 0; k0 < K; k0 += 32) {
        __syncthreads();
        stage16(aptr + k0,                    asl);
        stage16(aptr + k0 + (size_t)64 * K,   asl + 2048);
        stage16(bptr + k0,                    bsl);
        stage16(bptr + k0 + (size_t)64 * K,   bsl + 2048);
        __syncthreads();

        short8 af[4], bf[4];
        #pragma unroll
        for (int i = 0; i < 4; ++i)
            af[i] = *(const short8*)&As[(wr * 64 + i * 16 + fl) * 32 + fk];
        #pragma unroll
        for (int j = 0; j < 4; ++j)
            bf[j] = *(const short8*)&Bs[(wc * 64 + j * 16 + fl) * 32 + fk];
        #pragma unroll
        for (int i = 0; i < 4; ++i)
            #pragma unroll
            for (int j = 0; j < 4; ++j)
                acc[i][j] = __builtin_amdgcn_mfma_f32_16x16x32_bf16(af[i], bf[j], acc[i][j], 0, 0, 0);
    }

    #pragma unroll
    for (int i = 0; i < 4; ++i) {
        #pragma unroll
        for (int j = 0; j < 4; ++j) {
            #pragma unroll
            for (int q = 0; q < 4; ++q) {
                const int m = m0 + wr * 64 + i * 16 + (l >> 4) * 4 + q;
                const int n = n0 + wc * 64 + j * 16 + fl;
                const float vv = acc[i][j][q];
                if (MODE == 0) {
                    const int b = m >> 10, s = m & 1023, h = n >> 6, d = n & 63;
                    Cb[(((size_t)b * NH + h) * NS + s) * ND + d] = f2bf(vv);
                } else if (MODE == 3) {
                    const int h = m >> 6, d = m & 63, b = n >> 10, s = n & 1023;
                    Cb[(((size_t)b * NH + h) * ND + d) * NS + s] = f2bf(vv);
                } else {
                    Cf[(size_t)m * NE + n] = vv;
                }
            }
        }
    }
}

// ---------------- MFMA fused attention with RPE ----------------
__global__ __launch_bounds__(64)
void attn_mfma(const ushort* __restrict__ Qb, const ushort* __restrict__ Kb,
               const ushort* __restrict__ VTb, const ushort* __restrict__ PEKb,
               const ushort* __restrict__ PEVTs, ushort* __restrict__ AO)
{
    const int idx = blockIdx.x;
    const int st  = 31 - (idx >> 7);     // longest blocks first
    const int bh  = idx & 127;
    const int b   = bh >> 4, h = bh & 15;
    const int n2  = h * NB + b;          // torch view(S,H,B,S).transpose(0,2) shuffle
    const int b2  = n2 >> 4, h2 = n2 & 15;
    const int s0  = st * 32;

    const int lane = threadIdx.x;
    const int sl   = lane & 31;
    const int hi   = lane >> 5;

    __shared__ __align__(16) float  Mb[32][66];   // read stride 65 ≡ 1 mod 32
    __shared__ __align__(16) ushort Pb[32][72];

    for (int t = lane; t < 32 * 72 / 2; t += 64) ((int*)Pb)[t] = 0;

    const ushort* qptr  = Qb + (((size_t)bh * NS) + s0 + sl) * ND + hi * 8;
    const ushort* q2ptr = Qb + ((((size_t)b2 * NH + h2) * NS) + s0 + sl) * ND + hi * 8;
    short8 qf[4], q2f[4];
    #pragma unroll
    for (int c = 0; c < 4; ++c) {
        qf[c]  = *(const short8*)(qptr  + 16 * c);
        q2f[c] = *(const short8*)(q2ptr + 16 * c);
    }

    const ushort* kbase  = Kb  + (size_t)bh * NS * ND;
    const ushort* vtbase = VTb + (size_t)bh * ND * NS;

    f32x16 acc0 = {}, acc1 = {};
    float mrow = -1e30f, lrow = 0.f;

    for (int i = 0; i <= st; ++i) {
        const int t0 = i * 32;
        const int R0 = t0 - s0 + NL - 31;

        // ---- QK^T (swapped): Csw[t,s] ----
        f32x16 csw = {};
        const ushort* kptr = kbase + (size_t)(t0 + sl) * ND + hi * 8;
        #pragma unroll
        for (int c = 0; c < 4; ++c) {
            short8 kf = *(const short8*)(kptr + 16 * c);
            csw = __builtin_amdgcn_mfma_f32_32x32x16_bf16(kf, qf[c], csw, 0, 0, 0);
        }

        // ---- M[s,u] = q2[s]·pek[R0+u], u in [0,64) ----
        #pragma unroll
        for (int ch = 0; ch < 2; ++ch) {
            f32x16 cm = {};
            const ushort* pptr = PEKb + (size_t)(R0 + ch * 32 + sl) * ND + hi * 8;
            #pragma unroll
            for (int c = 0; c < 4; ++c) {
                short8 ef = *(const short8*)(pptr + 16 * c);
                cm = __builtin_amdgcn_mfma_f32_32x32x16_bf16(q2f[c], ef, cm, 0, 0, 0);
            }
            #pragma unroll
            for (int q = 0; q < 16; ++q) {
                const int srow = (q & 3) + 8 * (q >> 2) + 4 * hi;
                Mb[srow][ch * 32 + sl] = cm[q];
            }
        }
        __syncthreads();

        // ---- RPE gather + mask + online softmax ----
        float sc[16], tmax = -1e30f;
        #pragma unroll
        for (int q = 0; q < 16; ++q) {
            const int trow = (q & 3) + 8 * (q >> 2) + 4 * hi;
            const int u = trow + 31 - sl;
            float v = (csw[q] + Mb[sl][u]) * 0.125f;
            if (t0 + trow > s0 + sl) v = -1e30f;
            sc[q] = v;
            tmax = fmaxf(tmax, v);
        }
        tmax = fmaxf(tmax, __shfl_xor(tmax, 32));
        const float mnew = fmaxf(mrow, tmax);
        const float r = __expf(mrow - mnew);
        float ps[16], lsum = 0.f;
        #pragma unroll
        for (int q = 0; q < 16; ++q) { ps[q] = __expf(sc[q] - mnew); lsum += ps[q]; }
        lsum += __shfl_xor(lsum, 32);
        lrow = lrow * r + lsum;
        mrow = mnew;
        acc0 *= r; acc1 *= r;

        // ---- write Pskew (bf16) ----
        #pragma unroll
        for (int q = 0; q < 16; ++q) {
            const int trow = (q & 3) + 8 * (q >> 2) + 4 * hi;
            Pb[sl][trow + 31 - sl] = f2bf(ps[q]);
        }
        __syncthreads();

        // ---- PV: O^T += V^T · P^T ----
        float sh[16];
        #pragma unroll
        for (int q = 0; q < 16; ++q) sh[q] = __shfl_xor(ps[q], 32);
        #pragma unroll
        for (int c = 0; c < 2; ++c) {
            short8 bfrag;
            #pragma unroll
            for (int j = 0; j < 8; ++j) {
                float pv;
                if (j < 4) pv = hi ? sh[8 * c + 4 + j] : ps[8 * c + j];
                else       pv = hi ? ps[8 * c + j]     : sh[8 * c + j - 4];
                bfrag[j] = (short)f2bf(pv);
            }
            const ushort* vt0 = vtbase + (size_t)sl * NS + t0 + 16 * c + 8 * hi;
            short8 va0 = *(const short8*)(vt0);
            short8 va1 = *(const short8*)(vt0 + 32 * NS);
            acc0 = __builtin_amdgcn_mfma_f32_32x32x16_bf16(va0, bfrag, acc0, 0, 0, 0);
            acc1 = __builtin_amdgcn_mfma_f32_32x32x16_bf16(va1, bfrag, acc1, 0, 0, 0);
        }

        // ---- value-RPE skew GEMM: O^T += PEVT · Pskew^T ----
        #pragma unroll
        for (int c = 0; c < 4; ++c) {
            short8 pskew = *(const short8*)&Pb[sl][16 * c + 8 * hi];
            const ushort* pv0 = PEVTs + (size_t)sl * 1056 + (R0 - 1) + 16 * c + 8 * hi;
            short8 ea0 = *(const short8*)(pv0);
            short8 ea1 = *(const short8*)(pv0 + (size_t)32 * 1056);
            acc0 = __builtin_amdgcn_mfma_f32_32x32x16_bf16(ea0, pskew, acc0, 0, 0, 0);
            acc1 = __builtin_amdgcn_mfma_f32_32x32x16_bf16(ea1, pskew, acc1, 0, 0, 0);
        }
    }

    // ---- epilogue: bf16 packed stores ----
    const float inv = 1.0f / lrow;
    ushort* orow = AO + ((size_t)b * NS + s0 + sl) * NE + h * ND;
    #pragma unroll
    for (int g = 0; g < 4; ++g) {
        ushort4 o0 = make_ushort4(f2bf(acc0[4*g+0]*inv), f2bf(acc0[4*g+1]*inv),
                                  f2bf(acc0[4*g+2]*inv), f2bf(acc0[4*g+3]*inv));
        ushort4 o1 = make_ushort4(f2bf(acc1[4*g+0]*inv), f2bf(acc1[4*g+1]*inv),
                                  f2bf(acc1[4*g+2]*inv), f2bf(acc1[4*g+3]*inv));
        *(ushort4*)&orow[8 * g + 4 * hi]      = o0;
        *(ushort4*)&orow[8 * g + 4 * hi + 32] = o1;
    }
}

extern "C" void kernel_launch(void* const* d_in, const int* in_sizes, int n_in,
                              void* d_out, int out_size, void* d_ws, size_t ws_size,
                              hipStream_t stream) {
    const float* x   = (const float*)d_in[0];
    const float* Wq  = (const float*)d_in[2];
    const float* Wk  = (const float*)d_in[3];
    const float* Wv  = (const float*)d_in[4];
    const float* Wo  = (const float*)d_in[5];
    const float* pek = (const float*)d_in[6];
    const float* pev = (const float*)d_in[7];

    ushort* ws16 = (ushort*)d_ws;
    size_t off = 0;
    ushort* xb    = ws16 + off; off += (size_t)8388608;   // [8192,1024] bf16
    ushort* Wqb   = ws16 + off; off += (size_t)1048576;
    ushort* Wkb   = ws16 + off; off += (size_t)1048576;
    ushort* Wvb   = ws16 + off; off += (size_t)1048576;
    ushort* Wob   = ws16 + off; off += (size_t)1048576;
    ushort* Qb    = ws16 + off; off += (size_t)8388608;   // [B,H,S,D]
    ushort* Kbf   = ws16 + off; off += (size_t)8388608;   // [B,H,S,D]
    ushort* VTb   = ws16 + off; off += (size_t)8388608;   // [B,H,D,S]
    ushort* PEKb  = ws16 + off; off += (size_t)131136;    // [2049,64]
    ushort* PEVTs = ws16 + off; off += (size_t)67584;     // [64,1056]
    ushort* aob   = ws16 + off; off += (size_t)8388608;   // [B,S,E] bf16
    float*  out   = (float*)d_out;

    dim3 blk(256);
    cast_f2b4<<<8192, blk, 0, stream>>>(x,  xb,  2097152);
    cast_f2b4<<<1024, blk, 0, stream>>>(Wq, Wqb, 262144);
    cast_f2b4<<<1024, blk, 0, stream>>>(Wk, Wkb, 262144);
    cast_f2b4<<<1024, blk, 0, stream>>>(Wv, Wvb, 262144);
    cast_f2b4<<<1024, blk, 0, stream>>>(Wo, Wob, 262144);
    cast_pek<<<(2049 * 64 + 255) / 256, blk, 0, stream>>>(pek, PEKb, 2049 * 64);
    cast_pevt<<<(64 * 1056 + 255) / 256, blk, 0, stream>>>(pev, PEVTs);

    gemm_mfma<0><<<dim3(64, 8), blk, 0, stream>>>(xb, Wqb, nullptr, Qb);
    gemm_mfma<0><<<dim3(64, 8), blk, 0, stream>>>(xb, Wkb, nullptr, Kbf);
    gemm_mfma<3><<<dim3(8, 64), blk, 0, stream>>>(Wvb, xb, nullptr, VTb);

    attn_mfma<<<dim3(4096), dim3(64), 0, stream>>>(Qb, Kbf, VTb, PEKb, PEVTs, aob);

    gemm_mfma<1><<<dim3(64, 8), blk, 0, stream>>>(aob, Wob, out, nullptr);
}